// Round 5
// baseline (138.291 us; speedup 1.0000x reference)
//
#include <hip/hip_runtime.h>

static constexpr int NN  = 4194304;   // N
static constexpr int NB  = 4096;      // blocks; NB * TPB * 4 rows == NN
static constexpr int TPB = 256;

// ---------------------------------------------------------------------------
// R5 main kernel. Changes vs R4 (theory: wave transaction-count inflation):
//  * pred_actions loaded fully coalesced (3 lane-contiguous float4 per
//    thread = 16 lines/instr instead of 48), redistributed via LDS with a
//    +1-per-12-floats pad (stride 13, coprime with 32 banks -> <=2-way,
//    free per m136).
//  * neighbor tgt_prices from adjacent lane via shuffle; only lanes 0/63
//    touch global for the wave-boundary values.
// No device-scope fences/atomics (R3 lesson). Partials -> d_ws, 2nd launch.
// ---------------------------------------------------------------------------
__global__ __launch_bounds__(256) void pfl_main(
    const float* __restrict__ pp,   // pred_prices [N]
    const float* __restrict__ pa,   // pred_actions [N,3]
    const float* __restrict__ tp,   // tgt_prices [N]
    const int*   __restrict__ ta,   // tgt_actions [N] (int32)
    float* __restrict__ bsum)       // [3*NB] per-block partials
{
    const int tid = threadIdx.x;
    const int bid = blockIdx.x;
    const int g   = bid * TPB + tid;   // this thread's group of 4 rows
    const int i   = g * 4;

    const float4* pp4 = (const float4*)pp;
    const float4* tp4 = (const float4*)tp;
    const int4*   ta4 = (const int4*)ta;
    // block's pred_actions slice: rows [bid*1024, bid*1024+1024) = 768 float4
    const float4* paB = (const float4*)pa + (size_t)bid * (TPB * 3);

    // ---- all global loads issued up front (coalesced) ------------------
    float4 f0 = paB[tid];              // floats [4t   .. 4t+3 ]   of block slice
    float4 f1 = paB[tid + TPB];        // floats [1024+4t .. ]
    float4 f2 = paB[tid + 2 * TPB];    // floats [2048+4t .. ]
    float4 p  = pp4[g];
    float4 t  = tp4[g];
    int4   a  = ta4[g];

    // ---- neighbor tgt_prices via intra-wave shuffle --------------------
    const int lane = tid & 63;
    float tm1 = __shfl_up(t.w, 1, 64);     // lane-1's tp[i-1]
    float tnx = __shfl_down(t.x, 1, 64);   // lane+1's tp[i+4]
    if (lane == 0)  tm1 = (i > 0)      ? tp[i - 1] : 0.f;
    if (lane == 63) tnx = (i + 4 < NN) ? tp[i + 4] : 0.f;

    // ---- scatter pa into padded LDS: block-offset q -> 13*(q/12)+q%12 --
    __shared__ float lds[TPB * 13];    // 13312 B
    {
        float v[12] = {f0.x, f0.y, f0.z, f0.w,
                       f1.x, f1.y, f1.z, f1.w,
                       f2.x, f2.y, f2.z, f2.w};
        #pragma unroll
        for (int c = 0; c < 12; ++c) {
            int q = ((c >> 2) == 0 ? 0 : ((c >> 2) == 1 ? 1024 : 2048)) + 4 * tid + (c & 3);
            lds[13 * (q / 12) + (q % 12)] = v[c];
        }
    }
    __syncthreads();

    // thread t's 4 rows = 12 floats at padded offset 13*t (stride 13 -> 2-way max)
    float rows[4][3];
    #pragma unroll
    for (int j = 0; j < 4; ++j)
        #pragma unroll
        for (int c = 0; c < 3; ++c)
            rows[j][c] = lds[13 * tid + 3 * j + c];

    float tv[6] = {tm1, t.x, t.y, t.z, t.w, tnx};
    float pv[4] = {p.x, p.y, p.z, p.w};
    int   av[4] = {a.x, a.y, a.z, a.w};

    float sq = 0.f, ce = 0.f, pw = 0.f;

    #pragma unroll
    for (int j = 0; j < 4; ++j) {
        const int idx = i + j;
        // MSE
        float d = pv[j] - tv[j + 1];
        sq += d * d;

        // cross-entropy via logsumexp over 3 logits
        float x0 = rows[j][0], x1 = rows[j][1], x2 = rows[j][2];
        float m  = fmaxf(x0, fmaxf(x1, x2));
        float lse = m + __logf(__expf(x0 - m) + __expf(x1 - m) + __expf(x2 - m));
        float tgt = (av[j] == 0) ? x0 : ((av[j] == 1) ? x1 : x2);
        ce += lse - tgt;

        // argmax (first-max, matches jnp.argmax)
        int pidx = 0;
        float best = x0;
        if (x1 > best) { best = x1; pidx = 1; }
        if (x2 > best) { pidx = 2; }

        float profit = 0.f;
        if (pidx == 0)      profit = (idx + 1 < NN) ? (tv[j + 2] - tv[j + 1]) : 0.f;
        else if (pidx == 2) profit = (idx > 0)      ? (tv[j + 1] - tv[j])     : 0.f;

        pw += 1.f / (1.f + __expf(-10.f * profit));
    }

    // ---- block reduction (wave-64 shuffle -> LDS) ----------------------
    #pragma unroll
    for (int off = 32; off > 0; off >>= 1) {
        sq += __shfl_down(sq, off, 64);
        ce += __shfl_down(ce, off, 64);
        pw += __shfl_down(pw, off, 64);
    }

    __shared__ float s_sq[4], s_ce[4], s_pw[4];
    const int wid = tid >> 6;
    if (lane == 0) { s_sq[wid] = sq; s_ce[wid] = ce; s_pw[wid] = pw; }
    __syncthreads();

    if (tid == 0) {
        bsum[bid]          = s_sq[0] + s_sq[1] + s_sq[2] + s_sq[3];
        bsum[NB + bid]     = s_ce[0] + s_ce[1] + s_ce[2] + s_ce[3];
        bsum[2 * NB + bid] = s_pw[0] + s_pw[1] + s_pw[2] + s_pw[3];
    }
}

// ---------------------------------------------------------------------------
// Finalize: 1024 threads, float4 loads over the 3*4096 partials.
// out = 0.7 * (ce/N) * (pw/N) + 0.3 * (sq/N)
// ---------------------------------------------------------------------------
__global__ __launch_bounds__(1024) void pfl_final(const float* __restrict__ bsum,
                                                  float* __restrict__ out) {
    const int tid = threadIdx.x;
    const float4* b4 = (const float4*)bsum;
    const int Q = NB / 4;               // 1024 float4 per array

    float4 vsq = b4[tid];
    float4 vce = b4[Q + tid];
    float4 vpw = b4[2 * Q + tid];

    double sq = (double)vsq.x + vsq.y + vsq.z + vsq.w;
    double ce = (double)vce.x + vce.y + vce.z + vce.w;
    double pw = (double)vpw.x + vpw.y + vpw.z + vpw.w;

    #pragma unroll
    for (int off = 32; off > 0; off >>= 1) {
        sq += __shfl_down(sq, off, 64);
        ce += __shfl_down(ce, off, 64);
        pw += __shfl_down(pw, off, 64);
    }

    __shared__ double s_sq[16], s_ce[16], s_pw[16];
    const int lane = tid & 63;
    const int wid  = tid >> 6;
    if (lane == 0) { s_sq[wid] = sq; s_ce[wid] = ce; s_pw[wid] = pw; }
    __syncthreads();

    if (tid == 0) {
        double tsq = 0.0, tce = 0.0, tpw = 0.0;
        #pragma unroll
        for (int w = 0; w < 16; ++w) { tsq += s_sq[w]; tce += s_ce[w]; tpw += s_pw[w]; }
        const double inv = 1.0 / (double)NN;
        out[0] = (float)(0.7 * (tce * inv) * (tpw * inv) + 0.3 * (tsq * inv));
    }
}

extern "C" void kernel_launch(void* const* d_in, const int* in_sizes, int n_in,
                              void* d_out, int out_size, void* d_ws, size_t ws_size,
                              hipStream_t stream) {
    const float* pp = (const float*)d_in[0];   // pred_prices
    const float* pa = (const float*)d_in[1];   // pred_actions [N,3]
    const float* tp = (const float*)d_in[2];   // tgt_prices
    const int*   ta = (const int*)d_in[3];     // tgt_actions (int32)
    // d_in[4] (prices) unused by reference.

    float* bsum = (float*)d_ws;                // 3*NB floats = 48 KB (written, not RMW)

    pfl_main<<<NB, TPB, 0, stream>>>(pp, pa, tp, ta, bsum);
    pfl_final<<<1, 1024, 0, stream>>>(bsum, (float*)d_out);
}

// Round 6
// 137.769 us; speedup vs baseline: 1.0038x; 1.0038x over previous
//
#include <hip/hip_runtime.h>

static constexpr int NN  = 4194304;   // N
static constexpr int NB  = 1024;      // blocks
static constexpr int TPB = 256;
static constexpr int GPT = 4;         // groups of 4 rows per thread; NB*TPB*GPT*4 == NN

// ---------------------------------------------------------------------------
// R6 main kernel. Theory: R4/R5 were MLP/latency-bound (6-12 loads in flight
// per thread, short wave lifetime). GPT=4 with ALL 24 vmem loads hoisted
// back-to-back per thread; strided pa float4 loads direct (R5 proved the
// LDS-coalescing fix is neutral — cache absorbs stride-48B). Neighbors via
// intra-wave shuffle. No fences/atomics (R3 lesson).
// ---------------------------------------------------------------------------
__global__ __launch_bounds__(256) void pfl_main(
    const float* __restrict__ pp,   // pred_prices [N]
    const float* __restrict__ pa,   // pred_actions [N,3]
    const float* __restrict__ tp,   // tgt_prices [N]
    const int*   __restrict__ ta,   // tgt_actions [N] (int32)
    float* __restrict__ bsum)       // [3*NB] per-block partials
{
    const int tid  = threadIdx.x;
    const int bid  = blockIdx.x;
    const int base = bid * (TPB * GPT);       // first group of this block
    const int lane = tid & 63;

    const float4* pp4 = (const float4*)pp;
    const float4* tp4 = (const float4*)tp;
    const float4* pa4 = (const float4*)pa;
    const int4*   ta4 = (const int4*)ta;

    // ---- load phase: 24 independent vmem ops issued back-to-back -------
    float4 p[GPT], t[GPT], A0[GPT], A1[GPT], A2[GPT];
    int4   a[GPT];
    #pragma unroll
    for (int k = 0; k < GPT; ++k) {
        const int g = base + k * TPB + tid;
        p[k]  = pp4[g];
        t[k]  = tp4[g];
        a[k]  = ta4[g];
        A0[k] = pa4[3*g + 0];
        A1[k] = pa4[3*g + 1];
        A2[k] = pa4[3*g + 2];
    }

    float sq = 0.f, ce = 0.f, pw = 0.f;

    #pragma unroll
    for (int k = 0; k < GPT; ++k) {
        const int g = base + k * TPB + tid;
        const int i = g * 4;

        // neighbor tgt_prices via intra-wave shuffle; wave-edge lanes load
        // from global (guarded; L1/L2 hit)
        float tm1 = __shfl_up(t[k].w, 1, 64);
        float tnx = __shfl_down(t[k].x, 1, 64);
        if (lane == 0)  tm1 = (i > 0)      ? tp[i - 1] : 0.f;
        if (lane == 63) tnx = (i + 4 < NN) ? tp[i + 4] : 0.f;

        float tv[6] = {tm1, t[k].x, t[k].y, t[k].z, t[k].w, tnx};
        float pv[4] = {p[k].x, p[k].y, p[k].z, p[k].w};
        float rows[4][3] = {{A0[k].x, A0[k].y, A0[k].z},
                            {A0[k].w, A1[k].x, A1[k].y},
                            {A1[k].z, A1[k].w, A2[k].x},
                            {A2[k].y, A2[k].z, A2[k].w}};
        int av[4] = {a[k].x, a[k].y, a[k].z, a[k].w};

        #pragma unroll
        for (int j = 0; j < 4; ++j) {
            const int idx = i + j;
            // MSE
            float d = pv[j] - tv[j + 1];
            sq += d * d;

            // cross-entropy via logsumexp over 3 logits
            float x0 = rows[j][0], x1 = rows[j][1], x2 = rows[j][2];
            float m  = fmaxf(x0, fmaxf(x1, x2));
            float lse = m + __logf(__expf(x0 - m) + __expf(x1 - m) + __expf(x2 - m));
            float tgt = (av[j] == 0) ? x0 : ((av[j] == 1) ? x1 : x2);
            ce += lse - tgt;

            // argmax (first-max, matches jnp.argmax)
            int pidx = 0;
            float best = x0;
            if (x1 > best) { best = x1; pidx = 1; }
            if (x2 > best) { pidx = 2; }

            float profit = 0.f;
            if (pidx == 0)      profit = (idx + 1 < NN) ? (tv[j + 2] - tv[j + 1]) : 0.f;
            else if (pidx == 2) profit = (idx > 0)      ? (tv[j + 1] - tv[j])     : 0.f;

            pw += 1.f / (1.f + __expf(-10.f * profit));
        }
    }

    // ---- block reduction (wave-64 shuffle -> LDS) ----------------------
    #pragma unroll
    for (int off = 32; off > 0; off >>= 1) {
        sq += __shfl_down(sq, off, 64);
        ce += __shfl_down(ce, off, 64);
        pw += __shfl_down(pw, off, 64);
    }

    __shared__ float s_sq[4], s_ce[4], s_pw[4];
    const int wid = tid >> 6;
    if (lane == 0) { s_sq[wid] = sq; s_ce[wid] = ce; s_pw[wid] = pw; }
    __syncthreads();

    if (tid == 0) {
        bsum[bid]          = s_sq[0] + s_sq[1] + s_sq[2] + s_sq[3];
        bsum[NB + bid]     = s_ce[0] + s_ce[1] + s_ce[2] + s_ce[3];
        bsum[2 * NB + bid] = s_pw[0] + s_pw[1] + s_pw[2] + s_pw[3];
    }
}

// ---------------------------------------------------------------------------
// Finalize: 256 threads, float4 loads over the 3*1024 partials.
// out = 0.7 * (ce/N) * (pw/N) + 0.3 * (sq/N)
// ---------------------------------------------------------------------------
__global__ __launch_bounds__(256) void pfl_final(const float* __restrict__ bsum,
                                                 float* __restrict__ out) {
    const int tid = threadIdx.x;
    const float4* b4 = (const float4*)bsum;
    const int Q = NB / 4;               // 256 float4 per array

    float4 vsq = b4[tid];
    float4 vce = b4[Q + tid];
    float4 vpw = b4[2 * Q + tid];

    double sq = (double)vsq.x + vsq.y + vsq.z + vsq.w;
    double ce = (double)vce.x + vce.y + vce.z + vce.w;
    double pw = (double)vpw.x + vpw.y + vpw.z + vpw.w;

    #pragma unroll
    for (int off = 32; off > 0; off >>= 1) {
        sq += __shfl_down(sq, off, 64);
        ce += __shfl_down(ce, off, 64);
        pw += __shfl_down(pw, off, 64);
    }

    __shared__ double s_sq[4], s_ce[4], s_pw[4];
    const int lane = tid & 63;
    const int wid  = tid >> 6;
    if (lane == 0) { s_sq[wid] = sq; s_ce[wid] = ce; s_pw[wid] = pw; }
    __syncthreads();

    if (tid == 0) {
        double tsq = s_sq[0] + s_sq[1] + s_sq[2] + s_sq[3];
        double tce = s_ce[0] + s_ce[1] + s_ce[2] + s_ce[3];
        double tpw = s_pw[0] + s_pw[1] + s_pw[2] + s_pw[3];
        const double inv = 1.0 / (double)NN;
        out[0] = (float)(0.7 * (tce * inv) * (tpw * inv) + 0.3 * (tsq * inv));
    }
}

extern "C" void kernel_launch(void* const* d_in, const int* in_sizes, int n_in,
                              void* d_out, int out_size, void* d_ws, size_t ws_size,
                              hipStream_t stream) {
    const float* pp = (const float*)d_in[0];   // pred_prices
    const float* pa = (const float*)d_in[1];   // pred_actions [N,3]
    const float* tp = (const float*)d_in[2];   // tgt_prices
    const int*   ta = (const int*)d_in[3];     // tgt_actions (int32)
    // d_in[4] (prices) unused by reference.

    float* bsum = (float*)d_ws;                // 3*NB floats = 12 KB (written, not RMW)

    pfl_main<<<NB, TPB, 0, stream>>>(pp, pa, tp, ta, bsum);
    pfl_final<<<1, TPB, 0, stream>>>(bsum, (float*)d_out);
}

// Round 7
// 137.610 us; speedup vs baseline: 1.0049x; 1.0012x over previous
//
#include <hip/hip_runtime.h>

static constexpr int NN   = 4194304;  // N
static constexpr int NB   = 1024;     // blocks
static constexpr int TPB  = 256;
static constexpr int ITER = 4;        // NB*TPB*ITER*4 == NN
static constexpr int STRIDE = NB * TPB;   // group stride between iterations

// ---------------------------------------------------------------------------
// R7 main kernel. Theory: one-shot threads (R2/R4/R6) pay one un-overlapped
// vmcnt(0) wall per wave; sustained-BW kernels (fill @6.7 TB/s, m13 copy)
// use deep per-thread loops. Here: ITER=4 with explicit double-buffered
// register prefetch — iter k+1's 6 vector loads issue before iter k's
// compute, so the vmem queue never drains until the tail.
// No fences/atomics (R3 lesson). Partials -> d_ws, tiny second launch.
// ---------------------------------------------------------------------------
__global__ __launch_bounds__(256) void pfl_main(
    const float* __restrict__ pp,   // pred_prices [N]
    const float* __restrict__ pa,   // pred_actions [N,3]
    const float* __restrict__ tp,   // tgt_prices [N]
    const int*   __restrict__ ta,   // tgt_actions [N] (int32)
    float* __restrict__ bsum)       // [3*NB] per-block partials
{
    const int tid  = threadIdx.x;
    const int bid  = blockIdx.x;
    const int g0   = bid * TPB + tid;

    const float4* pp4 = (const float4*)pp;
    const float4* tp4 = (const float4*)tp;
    const float4* pa4 = (const float4*)pa;
    const int4*   ta4 = (const int4*)ta;

    // double-buffered register slots
    float4 P[2], T[2], B0[2], B1[2], B2[2];
    int4   A[2];
    float  TM[2], TX[2];

    // prologue: load iteration 0 into slot 0
    {
        const int g = g0;
        const int i = g * 4;
        P[0]  = pp4[g];
        T[0]  = tp4[g];
        A[0]  = ta4[g];
        B0[0] = pa4[3*g + 0];
        B1[0] = pa4[3*g + 1];
        B2[0] = pa4[3*g + 2];
        TM[0] = (i > 0)      ? tp[i - 1] : 0.f;
        TX[0] = (i + 4 < NN) ? tp[i + 4] : 0.f;
    }

    float sq = 0.f, ce = 0.f, pw = 0.f;

    #pragma unroll
    for (int k = 0; k < ITER; ++k) {
        const int cur = k & 1;
        const int nxt = cur ^ 1;

        // ---- prefetch iteration k+1 into the other slot ----------------
        if (k + 1 < ITER) {
            const int g = g0 + (k + 1) * STRIDE;
            const int i = g * 4;
            P[nxt]  = pp4[g];
            T[nxt]  = tp4[g];
            A[nxt]  = ta4[g];
            B0[nxt] = pa4[3*g + 0];
            B1[nxt] = pa4[3*g + 1];
            B2[nxt] = pa4[3*g + 2];
            TM[nxt] = (i > 0)      ? tp[i - 1] : 0.f;
            TX[nxt] = (i + 4 < NN) ? tp[i + 4] : 0.f;
        }

        // ---- compute iteration k ---------------------------------------
        const int g = g0 + k * STRIDE;
        const int i = g * 4;

        float tv[6] = {TM[cur], T[cur].x, T[cur].y, T[cur].z, T[cur].w, TX[cur]};
        float pv[4] = {P[cur].x, P[cur].y, P[cur].z, P[cur].w};
        float rows[4][3] = {{B0[cur].x, B0[cur].y, B0[cur].z},
                            {B0[cur].w, B1[cur].x, B1[cur].y},
                            {B1[cur].z, B1[cur].w, B2[cur].x},
                            {B2[cur].y, B2[cur].z, B2[cur].w}};
        int av[4] = {A[cur].x, A[cur].y, A[cur].z, A[cur].w};

        #pragma unroll
        for (int j = 0; j < 4; ++j) {
            const int idx = i + j;
            // MSE
            float d = pv[j] - tv[j + 1];
            sq += d * d;

            // cross-entropy via logsumexp over 3 logits
            float x0 = rows[j][0], x1 = rows[j][1], x2 = rows[j][2];
            float m  = fmaxf(x0, fmaxf(x1, x2));
            float lse = m + __logf(__expf(x0 - m) + __expf(x1 - m) + __expf(x2 - m));
            float tgt = (av[j] == 0) ? x0 : ((av[j] == 1) ? x1 : x2);
            ce += lse - tgt;

            // argmax (first-max, matches jnp.argmax)
            int pidx = 0;
            float best = x0;
            if (x1 > best) { best = x1; pidx = 1; }
            if (x2 > best) { pidx = 2; }

            float profit = 0.f;
            if (pidx == 0)      profit = (idx + 1 < NN) ? (tv[j + 2] - tv[j + 1]) : 0.f;
            else if (pidx == 2) profit = (idx > 0)      ? (tv[j + 1] - tv[j])     : 0.f;

            pw += 1.f / (1.f + __expf(-10.f * profit));
        }
    }

    // ---- block reduction (wave-64 shuffle -> LDS) ----------------------
    #pragma unroll
    for (int off = 32; off > 0; off >>= 1) {
        sq += __shfl_down(sq, off, 64);
        ce += __shfl_down(ce, off, 64);
        pw += __shfl_down(pw, off, 64);
    }

    __shared__ float s_sq[4], s_ce[4], s_pw[4];
    const int lane = tid & 63;
    const int wid  = tid >> 6;
    if (lane == 0) { s_sq[wid] = sq; s_ce[wid] = ce; s_pw[wid] = pw; }
    __syncthreads();

    if (tid == 0) {
        bsum[bid]          = s_sq[0] + s_sq[1] + s_sq[2] + s_sq[3];
        bsum[NB + bid]     = s_ce[0] + s_ce[1] + s_ce[2] + s_ce[3];
        bsum[2 * NB + bid] = s_pw[0] + s_pw[1] + s_pw[2] + s_pw[3];
    }
}

// ---------------------------------------------------------------------------
// Finalize: 256 threads, float4 loads over the 3*1024 partials.
// out = 0.7 * (ce/N) * (pw/N) + 0.3 * (sq/N)
// ---------------------------------------------------------------------------
__global__ __launch_bounds__(256) void pfl_final(const float* __restrict__ bsum,
                                                 float* __restrict__ out) {
    const int tid = threadIdx.x;
    const float4* b4 = (const float4*)bsum;
    const int Q = NB / 4;               // 256 float4 per array

    float4 vsq = b4[tid];
    float4 vce = b4[Q + tid];
    float4 vpw = b4[2 * Q + tid];

    double sq = (double)vsq.x + vsq.y + vsq.z + vsq.w;
    double ce = (double)vce.x + vce.y + vce.z + vce.w;
    double pw = (double)vpw.x + vpw.y + vpw.z + vpw.w;

    #pragma unroll
    for (int off = 32; off > 0; off >>= 1) {
        sq += __shfl_down(sq, off, 64);
        ce += __shfl_down(ce, off, 64);
        pw += __shfl_down(pw, off, 64);
    }

    __shared__ double s_sq[4], s_ce[4], s_pw[4];
    const int lane = tid & 63;
    const int wid  = tid >> 6;
    if (lane == 0) { s_sq[wid] = sq; s_ce[wid] = ce; s_pw[wid] = pw; }
    __syncthreads();

    if (tid == 0) {
        double tsq = s_sq[0] + s_sq[1] + s_sq[2] + s_sq[3];
        double tce = s_ce[0] + s_ce[1] + s_ce[2] + s_ce[3];
        double tpw = s_pw[0] + s_pw[1] + s_pw[2] + s_pw[3];
        const double inv = 1.0 / (double)NN;
        out[0] = (float)(0.7 * (tce * inv) * (tpw * inv) + 0.3 * (tsq * inv));
    }
}

extern "C" void kernel_launch(void* const* d_in, const int* in_sizes, int n_in,
                              void* d_out, int out_size, void* d_ws, size_t ws_size,
                              hipStream_t stream) {
    const float* pp = (const float*)d_in[0];   // pred_prices
    const float* pa = (const float*)d_in[1];   // pred_actions [N,3]
    const float* tp = (const float*)d_in[2];   // tgt_prices
    const int*   ta = (const int*)d_in[3];     // tgt_actions (int32)
    // d_in[4] (prices) unused by reference.

    float* bsum = (float*)d_ws;                // 3*NB floats = 12 KB (written, not RMW)

    pfl_main<<<NB, TPB, 0, stream>>>(pp, pa, tp, ta, bsum);
    pfl_final<<<1, TPB, 0, stream>>>(bsum, (float*)d_out);
}

// Round 8
// 132.419 us; speedup vs baseline: 1.0443x; 1.0392x over previous
//
#include <hip/hip_runtime.h>

static constexpr int NN  = 4194304;   // N
static constexpr int NB  = 4096;      // blocks; NB * TPB * 4 rows == NN
static constexpr int TPB = 256;

// ---------------------------------------------------------------------------
// FINAL (R4-best reproduction). One group of 4 rows per thread, direct
// float4/int4 loads, shuffle-free neighbor loads (L1 hits), no LDS staging,
// no device-scope fences/atomics (R3: per-block fences on 8 XCDs = 5x
// regression). Partials -> d_ws, tiny second launch.
//
// Measured R4-R7: schedule-insensitive at ~2.4-3.2 TB/s logical read — the
// read-path outstanding-request ceiling (write fills do 6.7 TB/s; copy and
// RMSNorm read-sides land at the same ~2.5-3.2). 96 MB of reads is
// irreducible => main ~30-40 us is the structural floor for this pattern.
// ---------------------------------------------------------------------------
__global__ __launch_bounds__(256) void pfl_main(
    const float* __restrict__ pp,   // pred_prices [N]
    const float* __restrict__ pa,   // pred_actions [N,3]
    const float* __restrict__ tp,   // tgt_prices [N]
    const int*   __restrict__ ta,   // tgt_actions [N] (int32)
    float* __restrict__ bsum)       // [3*NB] per-block partials
{
    const int tid = threadIdx.x;
    const int bid = blockIdx.x;
    const int g   = bid * TPB + tid;   // group of 4 rows
    const int i   = g * 4;

    const float4* pp4 = (const float4*)pp;
    const float4* tp4 = (const float4*)tp;
    const float4* pa4 = (const float4*)pa;
    const int4*   ta4 = (const int4*)ta;

    // ---- loads (all issued up front) -----------------------------------
    float4 p  = pp4[g];
    float4 t  = tp4[g];
    int4   a  = ta4[g];
    float4 A0 = pa4[3*g + 0];
    float4 A1 = pa4[3*g + 1];
    float4 A2 = pa4[3*g + 2];
    float tm1 = (i > 0)      ? tp[i - 1] : 0.f;   // L1 hits
    float tnx = (i + 4 < NN) ? tp[i + 4] : 0.f;

    float tv[6] = {tm1, t.x, t.y, t.z, t.w, tnx};
    float pv[4] = {p.x, p.y, p.z, p.w};
    float rows[4][3] = {{A0.x, A0.y, A0.z},
                        {A0.w, A1.x, A1.y},
                        {A1.z, A1.w, A2.x},
                        {A2.y, A2.z, A2.w}};
    int av[4] = {a.x, a.y, a.z, a.w};

    float sq = 0.f, ce = 0.f, pw = 0.f;

    #pragma unroll
    for (int j = 0; j < 4; ++j) {
        const int idx = i + j;
        // MSE
        float d = pv[j] - tv[j + 1];
        sq += d * d;

        // cross-entropy via logsumexp over 3 logits
        float x0 = rows[j][0], x1 = rows[j][1], x2 = rows[j][2];
        float m  = fmaxf(x0, fmaxf(x1, x2));
        float lse = m + __logf(__expf(x0 - m) + __expf(x1 - m) + __expf(x2 - m));
        float tgt = (av[j] == 0) ? x0 : ((av[j] == 1) ? x1 : x2);
        ce += lse - tgt;

        // argmax (first-max, matches jnp.argmax)
        int pidx = 0;
        float best = x0;
        if (x1 > best) { best = x1; pidx = 1; }
        if (x2 > best) { pidx = 2; }

        float profit = 0.f;
        if (pidx == 0)      profit = (idx + 1 < NN) ? (tv[j + 2] - tv[j + 1]) : 0.f;
        else if (pidx == 2) profit = (idx > 0)      ? (tv[j + 1] - tv[j])     : 0.f;

        pw += 1.f / (1.f + __expf(-10.f * profit));
    }

    // ---- block reduction (wave-64 shuffle -> LDS) ----------------------
    #pragma unroll
    for (int off = 32; off > 0; off >>= 1) {
        sq += __shfl_down(sq, off, 64);
        ce += __shfl_down(ce, off, 64);
        pw += __shfl_down(pw, off, 64);
    }

    __shared__ float s_sq[4], s_ce[4], s_pw[4];
    const int lane = tid & 63;
    const int wid  = tid >> 6;
    if (lane == 0) { s_sq[wid] = sq; s_ce[wid] = ce; s_pw[wid] = pw; }
    __syncthreads();

    if (tid == 0) {
        bsum[bid]          = s_sq[0] + s_sq[1] + s_sq[2] + s_sq[3];
        bsum[NB + bid]     = s_ce[0] + s_ce[1] + s_ce[2] + s_ce[3];
        bsum[2 * NB + bid] = s_pw[0] + s_pw[1] + s_pw[2] + s_pw[3];
    }
}

// ---------------------------------------------------------------------------
// Finalize: 1024 threads, float4 loads — each thread grabs one float4 from
// each of the three partial arrays (4096 floats = 1024 float4 each).
// out = 0.7 * (ce/N) * (pw/N) + 0.3 * (sq/N)
// ---------------------------------------------------------------------------
__global__ __launch_bounds__(1024) void pfl_final(const float* __restrict__ bsum,
                                                  float* __restrict__ out) {
    const int tid = threadIdx.x;
    const float4* b4 = (const float4*)bsum;
    const int Q = NB / 4;               // 1024 float4 per array

    float4 vsq = b4[tid];               // array 0: [0,   Q)
    float4 vce = b4[Q + tid];           // array 1: [Q,  2Q)
    float4 vpw = b4[2 * Q + tid];       // array 2: [2Q, 3Q)

    double sq = (double)vsq.x + vsq.y + vsq.z + vsq.w;
    double ce = (double)vce.x + vce.y + vce.z + vce.w;
    double pw = (double)vpw.x + vpw.y + vpw.z + vpw.w;

    #pragma unroll
    for (int off = 32; off > 0; off >>= 1) {
        sq += __shfl_down(sq, off, 64);
        ce += __shfl_down(ce, off, 64);
        pw += __shfl_down(pw, off, 64);
    }

    __shared__ double s_sq[16], s_ce[16], s_pw[16];
    const int lane = tid & 63;
    const int wid  = tid >> 6;
    if (lane == 0) { s_sq[wid] = sq; s_ce[wid] = ce; s_pw[wid] = pw; }
    __syncthreads();

    if (tid == 0) {
        double tsq = 0.0, tce = 0.0, tpw = 0.0;
        #pragma unroll
        for (int w = 0; w < 16; ++w) { tsq += s_sq[w]; tce += s_ce[w]; tpw += s_pw[w]; }
        const double inv = 1.0 / (double)NN;
        out[0] = (float)(0.7 * (tce * inv) * (tpw * inv) + 0.3 * (tsq * inv));
    }
}

extern "C" void kernel_launch(void* const* d_in, const int* in_sizes, int n_in,
                              void* d_out, int out_size, void* d_ws, size_t ws_size,
                              hipStream_t stream) {
    const float* pp = (const float*)d_in[0];   // pred_prices
    const float* pa = (const float*)d_in[1];   // pred_actions [N,3]
    const float* tp = (const float*)d_in[2];   // tgt_prices
    const int*   ta = (const int*)d_in[3];     // tgt_actions (int32)
    // d_in[4] (prices) unused by reference.

    float* bsum = (float*)d_ws;                // 3*NB floats = 48 KB (written, not RMW)

    pfl_main<<<NB, TPB, 0, stream>>>(pp, pa, tp, ta, bsum);
    pfl_final<<<1, 1024, 0, stream>>>(bsum, (float*)d_out);
}